// Round 9
// baseline (317.282 us; speedup 1.0000x reference)
//
#include <hip/hip_runtime.h>

// B-spline basis (Cox-de Boor), degree 3, 12 knots -> 8 basis functions.
// x: (1024, 8192) f32, knots: (12,) f32, out: (1024, 8192, 8) f32.
//
// R1: per-thread 128-B chunks -> store scatter -> kernel ~150 us.
// R2: block LDS transpose -> coalesced stores -> ~67 us (+~228-us harness
//     re-poison floor in dur_us; kernel never in rocprof top-5, fills are).
// R3/R7: ping-pong + prefetch + NT -> NULL (66 us).
// R8: barrier-free wave-private LDS transpose -> 61 us. Phase-bunching
//     theory refuted; residual suspect = the LDS round trip itself
//     (ds_write -> lgkmcnt -> ds_read -> lgkmcnt -> store, 2x ~120 cyc
//     latency on every wave's critical path per 4-KiB burst).
// R9: ZERO-LDS duplicate-compute transpose. Lanes 2m/2m+1 both compute the
//     full 8-basis pyramid for the same element (x load broadcasts to the
//     lane pair); each lane NT-stores the float4 half it owns. Coalesced
//     1-KiB wave bursts, no LDS, no lgkmcnt, independent waves. Compute
//     doubles but stays 3x under the memory budget. Target kernel ~50 us.

#define SEG 128  // elements per wave-iteration (1 KiB x-in, 4 KiB out)

typedef float vf4 __attribute__((ext_vector_type(4)));

__device__ __forceinline__ void compute_basis(
    float t, const float* __restrict__ k,
    const float* __restrict__ i1, const float* __restrict__ i2,
    const float* __restrict__ i3, float* __restrict__ B) {
  float tm[12];
#pragma unroll
  for (int i = 0; i < 12; ++i) tm[i] = t - k[i];

  // Level 0: half-open interval indicators [k[i], k[i+1]).
  float C[11];
#pragma unroll
  for (int i = 0; i < 11; ++i)
    C[i] = (k[i] <= t && t < k[i + 1]) ? 1.0f : 0.0f;

#pragma unroll
  for (int i = 0; i < 10; ++i)
    C[i] = tm[i] * i1[i] * C[i] - tm[i + 2] * i1[i + 1] * C[i + 1];
#pragma unroll
  for (int i = 0; i < 9; ++i)
    C[i] = tm[i] * i2[i] * C[i] - tm[i + 3] * i2[i + 1] * C[i + 1];
#pragma unroll
  for (int i = 0; i < 8; ++i)
    C[i] = tm[i] * i3[i] * C[i] - tm[i + 4] * i3[i + 1] * C[i + 1];

#pragma unroll
  for (int j = 0; j < 8; ++j) B[j] = C[j];
}

__global__ __launch_bounds__(256) void bspline_kernel(
    const float* __restrict__ x, const float* __restrict__ knots,
    float* __restrict__ out, int nseg) {
  // Knots are wave-uniform scalar loads; reciprocal denominators hoisted.
  float k[12];
#pragma unroll
  for (int i = 0; i < 12; ++i) k[i] = knots[i];
  float i1[11], i2[10], i3[9];
#pragma unroll
  for (int i = 0; i < 11; ++i) i1[i] = 1.0f / (k[i + 1] - k[i]);
#pragma unroll
  for (int i = 0; i < 10; ++i) i2[i] = 1.0f / (k[i + 2] - k[i]);
#pragma unroll
  for (int i = 0; i < 9; ++i) i3[i] = 1.0f / (k[i + 3] - k[i]);

  const int lane = threadIdx.x & 63;
  const int w = threadIdx.x >> 6;
  const int half = lane >> 1;        // element slot 0..31 within a sub-step
  const int j0 = (lane & 1) * 4;     // which float4 half this lane stores

  const int gstr = gridDim.x * 4;
  int g = blockIdx.x * 4 + w;
  if (g >= nseg) return;

  // Depth-2 x prefetch: 4 sub-step values per segment (2-lane broadcast each).
  float ta[4], tb[4];
#pragma unroll
  for (int s = 0; s < 4; ++s) ta[s] = x[(size_t)g * SEG + s * 32 + half];
  if (g + gstr < nseg) {
#pragma unroll
    for (int s = 0; s < 4; ++s)
      tb[s] = x[(size_t)(g + gstr) * SEG + s * 32 + half];
  }

  for (; g < nseg; g += gstr) {
    // Issue the prefetch for g+2*gstr before the compute+store burst.
    float tc[4];
    if (g + 2 * gstr < nseg) {
#pragma unroll
      for (int s = 0; s < 4; ++s)
        tc[s] = x[(size_t)(g + 2 * gstr) * SEG + s * 32 + half];
    }

    vf4* o4 = reinterpret_cast<vf4*>(out) + (size_t)g * (SEG * 2);
#pragma unroll
    for (int s = 0; s < 4; ++s) {
      // Both lanes of the pair compute element (s*32 + half) fully...
      float B[8];
      compute_basis(ta[s], k, i1, i2, i3, B);
      // ...and each stores its own half: fi = s*64 + lane, 16-B lane stride,
      // 1 KiB contiguous per wave store instruction. No LDS anywhere.
      vf4 v;
      v[0] = B[j0 + 0];
      v[1] = B[j0 + 1];
      v[2] = B[j0 + 2];
      v[3] = B[j0 + 3];
      __builtin_nontemporal_store(v, &o4[s * 64 + lane]);
    }

#pragma unroll
    for (int s = 0; s < 4; ++s) { ta[s] = tb[s]; tb[s] = tc[s]; }
  }
}

extern "C" void kernel_launch(void* const* d_in, const int* in_sizes, int n_in,
                              void* d_out, int out_size, void* d_ws, size_t ws_size,
                              hipStream_t stream) {
  const float* x = (const float*)d_in[0];
  const float* knots = (const float*)d_in[1];
  float* out = (float*)d_out;
  const int n = in_sizes[0];     // 8388608, divisible by SEG
  const int nseg = n / SEG;      // 65536 wave-segments
  const int blocks = 2048;       // no LDS: 8 blocks/CU, 32 waves/CU;
                                 // each wave handles exactly 8 segments
  bspline_kernel<<<blocks, 256, 0, stream>>>(x, knots, out, nseg);
}

// Round 10
// 290.901 us; speedup vs baseline: 1.0907x; 1.0907x over previous
//
#include <hip/hip_runtime.h>

// B-spline basis (Cox-de Boor), degree 3, 12 knots -> 8 basis functions.
// x: (1024, 8192) f32, knots: (12,) f32, out: (1024, 8192, 8) f32.
//
// R1: per-thread 128-B chunks -> store scatter -> kernel ~150 us.
// R2: block LDS transpose -> coalesced stores -> ~67 us (dur_us carries a
//     ~228-us harness re-poison floor; fills ~165-172 us own the top-5).
// R3/R7: ping-pong + prefetch + NT -> NULL (66 us).
// R8: barrier-free wave-private LDS transpose -> 61 us (best).
// R9: zero-LDS duplicate-compute -> 89 us REGRESSION. 2x VALU per element
//     cost far more than LDS latency saved. Reverted.
// R10: zero-LDS, SINGLE-compute, DPP lane-pair transpose. Lane 2m computes
//     elements {m, 64+m}, lane 2m+1 computes {32+m, 96+m}; each output
//     float4 needs only a 4-float exchange with lane^1 -> one v_mov_dpp
//     quad_perm:[1,0,3,2] per float on the VALU pipe. No LDS, no lgkmcnt,
//     no barriers, coalesced 1-KiB NT store bursts. Target kernel ~50 us.

#define SEG 128  // elements per wave-iteration (0.5 KiB x-in, 4 KiB out)

typedef float vf4 __attribute__((ext_vector_type(4)));

// value from lane^1 (quad_perm [1,0,3,2]), VALU pipe, no LDS.
__device__ __forceinline__ float xor1(float v) {
  return __int_as_float(
      __builtin_amdgcn_mov_dpp(__float_as_int(v), 0xB1, 0xF, 0xF, true));
}

__device__ __forceinline__ void compute_basis(
    float t, const float* __restrict__ k,
    const float* __restrict__ i1, const float* __restrict__ i2,
    const float* __restrict__ i3, float* __restrict__ B) {
  float tm[12];
#pragma unroll
  for (int i = 0; i < 12; ++i) tm[i] = t - k[i];

  // Level 0: half-open interval indicators [k[i], k[i+1]).
  float C[11];
#pragma unroll
  for (int i = 0; i < 11; ++i)
    C[i] = (k[i] <= t && t < k[i + 1]) ? 1.0f : 0.0f;

#pragma unroll
  for (int i = 0; i < 10; ++i)
    C[i] = tm[i] * i1[i] * C[i] - tm[i + 2] * i1[i + 1] * C[i + 1];
#pragma unroll
  for (int i = 0; i < 9; ++i)
    C[i] = tm[i] * i2[i] * C[i] - tm[i + 3] * i2[i + 1] * C[i + 1];
#pragma unroll
  for (int i = 0; i < 8; ++i)
    C[i] = tm[i] * i3[i] * C[i] - tm[i + 4] * i3[i + 1] * C[i + 1];

#pragma unroll
  for (int j = 0; j < 8; ++j) B[j] = C[j];
}

__global__ __launch_bounds__(256) void bspline_kernel(
    const float* __restrict__ x, const float* __restrict__ knots,
    float* __restrict__ out, int nseg) {
  // Knots are wave-uniform scalar loads; reciprocal denominators hoisted.
  float k[12];
#pragma unroll
  for (int i = 0; i < 12; ++i) k[i] = knots[i];
  float i1[11], i2[10], i3[9];
#pragma unroll
  for (int i = 0; i < 11; ++i) i1[i] = 1.0f / (k[i + 1] - k[i]);
#pragma unroll
  for (int i = 0; i < 10; ++i) i2[i] = 1.0f / (k[i + 2] - k[i]);
#pragma unroll
  for (int i = 0; i < 9; ++i) i3[i] = 1.0f / (k[i + 3] - k[i]);

  const int lane = threadIdx.x & 63;
  const int w = threadIdx.x >> 6;
  const bool p = (lane & 1) != 0;     // parity within the exchange pair
  const int e0 = (lane & 1) * 32 + (lane >> 1);  // owned elements: e0, e0+64

  const int gstr = gridDim.x * 4;
  int g = blockIdx.x * 4 + w;
  if (g >= nseg) return;

  // Depth-2 x prefetch (2 scalar loads per segment; wave covers a
  // contiguous 512-B span per segment -> coalesces fine).
  float t0a = x[(size_t)g * SEG + e0];
  float t1a = x[(size_t)g * SEG + e0 + 64];
  float t0b, t1b;
  if (g + gstr < nseg) {
    t0b = x[(size_t)(g + gstr) * SEG + e0];
    t1b = x[(size_t)(g + gstr) * SEG + e0 + 64];
  }

  for (; g < nseg; g += gstr) {
    float t0c, t1c;
    if (g + 2 * gstr < nseg) {
      t0c = x[(size_t)(g + 2 * gstr) * SEG + e0];
      t1c = x[(size_t)(g + 2 * gstr) * SEG + e0 + 64];
    }

    float Ba[8], Bb[8];
    compute_basis(t0a, k, i1, i2, i3, Ba);
    compute_basis(t1a, k, i1, i2, i3, Bb);

    // Split each 8-vector into the half this lane stores (keep) and the
    // half its XOR-1 partner stores (send); exchange sends via DPP.
    float keepA[4], keepB[4], recvA[4], recvB[4];
#pragma unroll
    for (int i = 0; i < 4; ++i) {
      keepA[i] = p ? Ba[4 + i] : Ba[i];
      recvA[i] = xor1(p ? Ba[i] : Ba[4 + i]);
      keepB[i] = p ? Bb[4 + i] : Bb[i];
      recvB[i] = xor1(p ? Bb[i] : Bb[4 + i]);
    }

    // Store: fi = s*64+lane -> element s*32+(lane>>1), basis half (lane&1)*4.
    //   s=0: elem m     (even pair-member's e0): even keeps, odd receives.
    //   s=1: elem 32+m  (odd's e0):  even receives, odd keeps.
    //   s=2: elem 64+m  (even's e1). s=3: elem 96+m (odd's e1).
    vf4* o4 = reinterpret_cast<vf4*>(out) + (size_t)g * 256;
    vf4 D0, D1, D2, D3;
#pragma unroll
    for (int i = 0; i < 4; ++i) {
      D0[i] = p ? recvA[i] : keepA[i];
      D1[i] = p ? keepA[i] : recvA[i];
      D2[i] = p ? recvB[i] : keepB[i];
      D3[i] = p ? keepB[i] : recvB[i];
    }
    __builtin_nontemporal_store(D0, &o4[0 * 64 + lane]);  // 1 KiB/wave instr
    __builtin_nontemporal_store(D1, &o4[1 * 64 + lane]);
    __builtin_nontemporal_store(D2, &o4[2 * 64 + lane]);
    __builtin_nontemporal_store(D3, &o4[3 * 64 + lane]);

    t0a = t0b; t1a = t1b;
    t0b = t0c; t1b = t1c;
  }
}

extern "C" void kernel_launch(void* const* d_in, const int* in_sizes, int n_in,
                              void* d_out, int out_size, void* d_ws, size_t ws_size,
                              hipStream_t stream) {
  const float* x = (const float*)d_in[0];
  const float* knots = (const float*)d_in[1];
  float* out = (float*)d_out;
  const int n = in_sizes[0];     // 8388608, divisible by SEG
  const int nseg = n / SEG;      // 65536 wave-segments
  const int blocks = 2048;       // no LDS; each wave handles 8 segments
  bspline_kernel<<<blocks, 256, 0, stream>>>(x, knots, out, nseg);
}